// Round 11
// baseline (3350.304 us; speedup 1.0000x reference)
//
#include <hip/hip_runtime.h>
#include <hip/hip_bf16.h>
#include <stdint.h>

#define E_N 16
#define TOPK 4
#define DD 2560
#define FF 1664
#define FSS 3328
#define TT 2048

typedef __attribute__((ext_vector_type(8))) __bf16 bf16x8;
typedef __attribute__((ext_vector_type(4))) float f32x4;

__device__ __forceinline__ unsigned short f2bf(float f) {
  return __builtin_bit_cast(unsigned short, (__bf16)f);
}

#define GLOAD16(g, l)                                                          \
  __builtin_amdgcn_global_load_lds(                                            \
      (const __attribute__((address_space(1))) void*)(g),                      \
      (__attribute__((address_space(3))) void*)(l), 16, 0, 0)

// swizzled block decompose: XCD-chunked bijective remap (requires nwg%8==0)
__device__ __forceinline__ void swz_block(int& bm, int& bn, int& bz) {
  int gx = gridDim.x, gy = gridDim.y;
  int nwg = gx * gy * gridDim.z;
  int flat = blockIdx.x + gx * (blockIdx.y + gy * blockIdx.z);
  if ((nwg & 7) == 0) flat = (flat & 7) * (nwg >> 3) + (flat >> 3);
  bm = flat % gx;
  int rest = flat / gx;
  bn = rest % gy;
  bz = rest / gy;
}

// ---------------- X -> bf16 ----------------
__global__ __launch_bounds__(256) void cvt_bf16_kernel(const float* __restrict__ in,
                                                       unsigned short* __restrict__ out) {
  size_t i = ((size_t)blockIdx.x * 256 + threadIdx.x) * 4;
  float4 v = *reinterpret_cast<const float4*>(in + i);
  ushort4 o;
  o.x = f2bf(v.x); o.y = f2bf(v.y); o.z = f2bf(v.z); o.w = f2bf(v.w);
  *reinterpret_cast<ushort4*>(out + i) = o;
}

// ---------------- Router ----------------
__global__ __launch_bounds__(256) void router_kernel(const float* __restrict__ x,
                                                     const float* __restrict__ rw,
                                                     int* __restrict__ cnt,
                                                     int* __restrict__ list,
                                                     float* __restrict__ tw) {
  int t = blockIdx.x;
  const float* xr = x + (size_t)t * DD;
  __shared__ float logits[E_N];
  int lane = threadIdx.x & 63, wid = threadIdx.x >> 6;
  for (int ee = 0; ee < 4; ++ee) {
    int e = wid * 4 + ee;
    const float* wr = rw + (size_t)e * DD;
    float p = 0.f;
    for (int d = lane; d < DD; d += 64) p += xr[d] * wr[d];
#pragma unroll
    for (int off = 32; off > 0; off >>= 1) p += __shfl_down(p, off);
    if (lane == 0) logits[e] = p;
  }
  __syncthreads();
  if (threadIdx.x == 0) {
    float mx = -1e30f;
    for (int e = 0; e < E_N; ++e) mx = fmaxf(mx, logits[e]);
    float pe[E_N];
    for (int e = 0; e < E_N; ++e) pe[e] = __expf(logits[e] - mx);
    int idx[TOPK]; float val[TOPK]; float s4 = 0.f;
    unsigned used = 0;
    for (int k = 0; k < TOPK; ++k) {
      int bi = 0; float bv = -1.f;
      for (int e = 0; e < E_N; ++e)
        if (!((used >> e) & 1) && pe[e] > bv) { bv = pe[e]; bi = e; }
      used |= 1u << bi; idx[k] = bi; val[k] = bv; s4 += bv;
    }
    float inv = 1.f / s4;
    for (int k = 0; k < TOPK; ++k) {
      int e2 = idx[k];
      int pos = atomicAdd(&cnt[e2], 1);
      list[e2 * TT + pos] = t * 4 + k;
      tw[t * 4 + k] = val[k] * inv;
    }
  }
}

// ======================= fused gate+up, native f32 weights =======================
// 128x128 output tile per matrix, BK=64, 4 waves (2m x 2n), single-buffer 80KB LDS:
//   ldsA : A bf16 [128 rows][64 k]  (16KB, 128B rows, chunk swz c^(row&7))
//   ldsG/U : W f32 [64 k][128 n]    (32KB each, native rows, chunk swz c^(((k>>3)&1)<<2))
// B-fragments built by 8x ds_read_b32 column reads (512B stride, 2-way banks = free).
// z: 0..15 experts (gathered rows, out Hx), 16 shared (out Hs). Epilogue: silu(g)*u.
__global__ __launch_bounds__(256, 2) void guf_kernel(
    const unsigned short* __restrict__ Xb,
    const float* __restrict__ Wg, const float* __restrict__ Wu,
    const float* __restrict__ Sg, const float* __restrict__ Su,
    unsigned short* __restrict__ Hx, unsigned short* __restrict__ Hs,
    const int* __restrict__ list, const int* __restrict__ cnt) {
  int bm, bn, z;
  swz_block(bm, bn, z);
  const float *G0, *U0;
  unsigned short* O0;
  const int* lst = nullptr;
  int M, Nt;
  if (z < E_N) {
    M = cnt[z]; lst = list + z * TT; Nt = FF;
    G0 = Wg + (size_t)z * DD * FF; U0 = Wu + (size_t)z * DD * FF; O0 = Hx;
  } else {
    M = TT; Nt = FSS; G0 = Sg; U0 = Su; O0 = Hs;
  }
  int m0 = bm * 128, n0 = bn * 128;
  if (m0 >= M || n0 >= Nt) return;

  __shared__ __align__(16) unsigned short ldsA[8192];
  __shared__ __align__(16) float ldsG[8192];
  __shared__ __align__(16) float ldsU[8192];

  int tid = threadIdx.x, lane = tid & 63, w = tid >> 6;

  // A staging: 4 chunks/thread, bf16 gather rows
  const unsigned short* pA[4];
#pragma unroll
  for (int j = 0; j < 4; ++j) {
    int q = j * 256 + tid;
    int row = q >> 3, c = q & 7;
    int cs = c ^ (row & 7);
    int ar = min(m0 + row, M - 1);
    int code = lst ? lst[ar] : ar;
    int tok = lst ? (code >> 2) : code;
    pA[j] = Xb + (size_t)tok * DD + cs * 8;
  }
  // B staging offsets: 8 chunks/thread per matrix (shared mapping)
  int offB[8];
#pragma unroll
  for (int j = 0; j < 8; ++j) {
    int q = j * 256 + tid;
    int k = q >> 5, cd = q & 31;
    int cs = cd ^ (((k >> 3) & 1) << 2);
    offB[j] = k * Nt + cs * 4;
  }

  auto issue = [&](int kt) {
    size_t ko = (size_t)kt * 64;
#pragma unroll
    for (int j = 0; j < 4; ++j)
      GLOAD16(pA[j] + ko, ldsA + (j * 256 + tid) * 8);
    const float* gb = G0 + n0 + ko * Nt;
    const float* ub = U0 + n0 + ko * Nt;
#pragma unroll
    for (int j = 0; j < 8; ++j) {
      GLOAD16(gb + offB[j], ldsG + (j * 256 + tid) * 4);
      GLOAD16(ub + offB[j], ldsU + (j * 256 + tid) * 4);
    }
  };

  int wr = (w >> 1) * 64, wc = (w & 1) * 64;
  int aoff[4][2], bb[4][2];
#pragma unroll
  for (int m = 0; m < 4; ++m) {
    int r = wr + m * 16 + (lane & 15);
#pragma unroll
    for (int kh = 0; kh < 2; ++kh) {
      int cg = kh * 4 + (lane >> 4);
      aoff[m][kh] = r * 64 + ((cg ^ (r & 7)) * 8);
    }
  }
#pragma unroll
  for (int nf = 0; nf < 4; ++nf) {
    int nl = wc + nf * 16 + (lane & 15);
#pragma unroll
    for (int kh = 0; kh < 2; ++kh) {
      int k0 = kh * 32 + (lane >> 4) * 8;
      int f = ((lane >> 4) & 1) << 2;
      bb[nf][kh] = k0 * 128 + ((((nl >> 2) & 31) ^ f) << 2) + (nl & 3);
    }
  }

  f32x4 accG[4][4] = {};
  f32x4 accU[4][4] = {};

  int nk = DD / 64;
  issue(0);
  for (int kt = 0; kt < nk; ++kt) {
    __syncthreads();  // drains vmcnt(0): tile fully in LDS
#pragma unroll
    for (int kh = 0; kh < 2; ++kh) {
      bf16x8 a[4], g[4], u[4];
#pragma unroll
      for (int m = 0; m < 4; ++m)
        a[m] = __builtin_bit_cast(bf16x8, *reinterpret_cast<const uint4*>(ldsA + aoff[m][kh]));
#pragma unroll
      for (int nf = 0; nf < 4; ++nf) {
        int b0 = bb[nf][kh];
#pragma unroll
        for (int j = 0; j < 8; ++j) {
          g[nf][j] = (__bf16)ldsG[b0 + j * 128];
          u[nf][j] = (__bf16)ldsU[b0 + j * 128];
        }
      }
      __builtin_amdgcn_s_setprio(1);
#pragma unroll
      for (int m = 0; m < 4; ++m)
#pragma unroll
        for (int nf = 0; nf < 4; ++nf) {
          accG[m][nf] = __builtin_amdgcn_mfma_f32_16x16x32_bf16(a[m], g[nf], accG[m][nf], 0, 0, 0);
          accU[m][nf] = __builtin_amdgcn_mfma_f32_16x16x32_bf16(a[m], u[nf], accU[m][nf], 0, 0, 0);
        }
      __builtin_amdgcn_s_setprio(0);
    }
    __syncthreads();  // all waves done reading buffer
    if (kt + 1 < nk) issue(kt + 1);
  }

  // epilogue: h = silu(g)*u -> bf16 at row=code
#pragma unroll
  for (int m = 0; m < 4; ++m) {
#pragma unroll
    for (int q = 0; q < 4; ++q) {
      int lr = wr + m * 16 + (lane >> 4) * 4 + q;
      int grow = m0 + lr;
      if (grow < M) {
        int code = lst ? lst[grow] : grow;
        unsigned short* Hp = O0 + (size_t)code * Nt + n0 + wc + (lane & 15);
#pragma unroll
        for (int nf = 0; nf < 4; ++nf) {
          float gg = accG[m][nf][q], uu = accU[m][nf][q];
          Hp[nf * 16] = f2bf((gg / (1.f + __expf(-gg))) * uu);
        }
      }
    }
  }
}

// ======================= down GEMM, native f32 weights =======================
// A = H bf16 (gathered), B = Wd [K][N] f32 native. 48KB LDS -> 3 blocks/CU.
// z: 0..15 experts (out Y, scaled by tw), 16 shared (out Ys).
__global__ __launch_bounds__(256, 3) void dnf_kernel(
    const unsigned short* __restrict__ Hx, const unsigned short* __restrict__ Hs,
    const float* __restrict__ Wd, const float* __restrict__ Sd,
    float* __restrict__ Y, float* __restrict__ Ys,
    const int* __restrict__ list, const int* __restrict__ cnt,
    const float* __restrict__ tw) {
  int bm, bn, z;
  swz_block(bm, bn, z);
  const unsigned short* A0;
  const float* B0;
  float* O0;
  const int* lst = nullptr;
  const float* sc = nullptr;
  int M, Kt;
  if (z < E_N) {
    M = cnt[z]; lst = list + z * TT; Kt = FF;
    A0 = Hx; B0 = Wd + (size_t)z * FF * DD; O0 = Y; sc = tw;
  } else {
    M = TT; Kt = FSS; A0 = Hs; B0 = Sd; O0 = Ys;
  }
  int m0 = bm * 128, n0 = bn * 128;
  if (m0 >= M) return;

  __shared__ __align__(16) unsigned short ldsA[8192];
  __shared__ __align__(16) float ldsB[8192];

  int tid = threadIdx.x, lane = tid & 63, w = tid >> 6;

  const unsigned short* pA[4];
#pragma unroll
  for (int j = 0; j < 4; ++j) {
    int q = j * 256 + tid;
    int row = q >> 3, c = q & 7;
    int cs = c ^ (row & 7);
    int ar = min(m0 + row, M - 1);
    int code = lst ? lst[ar] : ar;
    pA[j] = A0 + (size_t)code * Kt + cs * 8;
  }
  int offB[8];
#pragma unroll
  for (int j = 0; j < 8; ++j) {
    int q = j * 256 + tid;
    int k = q >> 5, cd = q & 31;
    int cs = cd ^ (((k >> 3) & 1) << 2);
    offB[j] = k * DD + cs * 4;
  }

  auto issue = [&](int kt) {
    size_t ko = (size_t)kt * 64;
#pragma unroll
    for (int j = 0; j < 4; ++j)
      GLOAD16(pA[j] + ko, ldsA + (j * 256 + tid) * 8);
    const float* bbase = B0 + n0 + ko * DD;
#pragma unroll
    for (int j = 0; j < 8; ++j)
      GLOAD16(bbase + offB[j], ldsB + (j * 256 + tid) * 4);
  };

  int wr = (w >> 1) * 64, wc = (w & 1) * 64;
  int aoff[4][2], bb[4][2];
#pragma unroll
  for (int m = 0; m < 4; ++m) {
    int r = wr + m * 16 + (lane & 15);
#pragma unroll
    for (int kh = 0; kh < 2; ++kh) {
      int cg = kh * 4 + (lane >> 4);
      aoff[m][kh] = r * 64 + ((cg ^ (r & 7)) * 8);
    }
  }
#pragma unroll
  for (int nf = 0; nf < 4; ++nf) {
    int nl = wc + nf * 16 + (lane & 15);
#pragma unroll
    for (int kh = 0; kh < 2; ++kh) {
      int k0 = kh * 32 + (lane >> 4) * 8;
      int f = ((lane >> 4) & 1) << 2;
      bb[nf][kh] = k0 * 128 + ((((nl >> 2) & 31) ^ f) << 2) + (nl & 3);
    }
  }

  f32x4 acc[4][4] = {};

  int nk = Kt / 64;
  issue(0);
  for (int kt = 0; kt < nk; ++kt) {
    __syncthreads();
#pragma unroll
    for (int kh = 0; kh < 2; ++kh) {
      bf16x8 a[4], b[4];
#pragma unroll
      for (int m = 0; m < 4; ++m)
        a[m] = __builtin_bit_cast(bf16x8, *reinterpret_cast<const uint4*>(ldsA + aoff[m][kh]));
#pragma unroll
      for (int nf = 0; nf < 4; ++nf) {
        int b0 = bb[nf][kh];
#pragma unroll
        for (int j = 0; j < 8; ++j) b[nf][j] = (__bf16)ldsB[b0 + j * 128];
      }
      __builtin_amdgcn_s_setprio(1);
#pragma unroll
      for (int m = 0; m < 4; ++m)
#pragma unroll
        for (int nf = 0; nf < 4; ++nf)
          acc[m][nf] = __builtin_amdgcn_mfma_f32_16x16x32_bf16(a[m], b[nf], acc[m][nf], 0, 0, 0);
      __builtin_amdgcn_s_setprio(0);
    }
    __syncthreads();
    if (kt + 1 < nk) issue(kt + 1);
  }

#pragma unroll
  for (int m = 0; m < 4; ++m) {
#pragma unroll
    for (int q = 0; q < 4; ++q) {
      int lr = wr + m * 16 + (lane >> 4) * 4 + q;
      int grow = m0 + lr;
      if (grow < M) {
        int code = lst ? lst[grow] : grow;
        float scale = sc ? sc[code] : 1.f;
        float* Op = O0 + (size_t)code * DD + n0 + wc + (lane & 15);
#pragma unroll
        for (int nf = 0; nf < 4; ++nf) Op[nf * 16] = acc[m][nf][q] * scale;
      }
    }
  }
}

// ---------------- combine ----------------
__global__ __launch_bounds__(256) void combine_kernel(const float* __restrict__ Y,
                                                      const float* __restrict__ Ys,
                                                      float* __restrict__ out) {
  size_t i = ((size_t)blockIdx.x * 256 + threadIdx.x) * 4;
  size_t t = i / DD;
  int d = (int)(i % DD);
  float4 a = *reinterpret_cast<const float4*>(Ys + i);
#pragma unroll
  for (int k = 0; k < 4; ++k) {
    float4 v = *reinterpret_cast<const float4*>(Y + (t * 4 + k) * (size_t)DD + d);
    a.x += v.x; a.y += v.y; a.z += v.z; a.w += v.w;
  }
  *reinterpret_cast<float4*>(out + i) = a;
}

extern "C" void kernel_launch(void* const* d_in, const int* in_sizes, int n_in,
                              void* d_out, int out_size, void* d_ws, size_t ws_size,
                              hipStream_t stream) {
  const float* x  = (const float*)d_in[0];
  const float* rw = (const float*)d_in[1];
  const float* wg = (const float*)d_in[2];
  const float* wu = (const float*)d_in[3];
  const float* wd = (const float*)d_in[4];
  const float* sg = (const float*)d_in[5];
  const float* su = (const float*)d_in[6];
  const float* sd = (const float*)d_in[7];
  float* out = (float*)d_out;

  char* ws = (char*)d_ws;
  size_t off = 0;
  auto alloc = [&](size_t bytes) {
    off = (off + 255) & ~(size_t)255;
    void* p = ws + off;
    off += bytes;
    return p;
  };
  unsigned short* Xb = (unsigned short*)alloc((size_t)TT * DD * 2);
  unsigned short* Hx = (unsigned short*)alloc((size_t)4 * TT * FF * 2);
  unsigned short* Hs = (unsigned short*)alloc((size_t)TT * FSS * 2);
  float* Y  = (float*)alloc((size_t)4 * TT * DD * 4);
  float* Ys = (float*)alloc((size_t)TT * DD * 4);
  float* tw = (float*)alloc((size_t)4 * TT * 4);
  int* cnt  = (int*)alloc(E_N * 4);
  int* list = (int*)alloc((size_t)E_N * TT * 4);
  (void)ws_size; (void)in_sizes; (void)n_in; (void)out_size;

  hipMemsetAsync(cnt, 0, E_N * 4, stream);
  cvt_bf16_kernel<<<TT * DD / 4 / 256, 256, 0, stream>>>(x, Xb);
  router_kernel<<<TT, 256, 0, stream>>>(x, rw, cnt, list, tw);

  // fused gate+up, native f32 weights (z: 16 experts + 1 shared); gy covers FSS
  guf_kernel<<<dim3(TT / 128, FSS / 128, E_N + 1), 256, 0, stream>>>(
      Xb, wg, wu, sg, su, Hx, Hs, list, cnt);

  // down, native f32 weights (z: 16 experts + 1 shared)
  dnf_kernel<<<dim3(TT / 128, DD / 128, E_N + 1), 256, 0, stream>>>(
      Hx, Hs, wd, sd, Y, Ys, list, cnt, tw);

  combine_kernel<<<TT * DD / 4 / 256, 256, 0, stream>>>(Y, Ys, out);
}

// Round 12
// 1312.417 us; speedup vs baseline: 2.5528x; 2.5528x over previous
//
#include <hip/hip_runtime.h>
#include <hip/hip_bf16.h>
#include <stdint.h>

#define E_N 16
#define TOPK 4
#define DD 2560
#define FF 1664
#define FSS 3328
#define TT 2048

typedef __attribute__((ext_vector_type(8))) __bf16 bf16x8;
typedef __attribute__((ext_vector_type(4))) float f32x4;

__device__ __forceinline__ unsigned short f2bf(float f) {
  return __builtin_bit_cast(unsigned short, (__bf16)f);
}
__device__ __forceinline__ float bf2f(unsigned short u) {
  return __builtin_bit_cast(float, (unsigned int)u << 16);
}
__device__ __forceinline__ unsigned int pk2(float a, float b) {
  return (unsigned int)f2bf(a) | ((unsigned int)f2bf(b) << 16);
}

#define GLOAD16(g, l)                                                          \
  __builtin_amdgcn_global_load_lds(                                            \
      (const __attribute__((address_space(1))) void*)(g),                      \
      (__attribute__((address_space(3))) void*)(l), 16, 0, 0)

#define SBAR() __builtin_amdgcn_s_barrier()
#define VMW(N) asm volatile("s_waitcnt vmcnt(" #N ")" ::: "memory")

// swizzled block decompose: XCD-chunked bijective remap (requires nwg%8==0)
__device__ __forceinline__ void swz_block(int& bm, int& bn, int& bz) {
  int gx = gridDim.x, gy = gridDim.y;
  int nwg = gx * gy * gridDim.z;
  int flat = blockIdx.x + gx * (blockIdx.y + gy * blockIdx.z);
  if ((nwg & 7) == 0) flat = (flat & 7) * (nwg >> 3) + (flat >> 3);
  bm = flat % gx;
  int rest = flat / gx;
  bn = rest % gy;
  bz = rest / gy;
}

// ---------------- X -> bf16 ----------------
__global__ __launch_bounds__(256) void cvt_bf16_kernel(const float* __restrict__ in,
                                                       unsigned short* __restrict__ out) {
  size_t i = ((size_t)blockIdx.x * 256 + threadIdx.x) * 4;
  float4 v = *reinterpret_cast<const float4*>(in + i);
  ushort4 o;
  o.x = f2bf(v.x); o.y = f2bf(v.y); o.z = f2bf(v.z); o.w = f2bf(v.w);
  *reinterpret_cast<ushort4*>(out + i) = o;
}

// ---------------- weight transpose+convert: [K][N] f32 -> [N][K] bf16 ----------------
__global__ __launch_bounds__(256) void tcvt_kernel(const float* __restrict__ in,
                                                   unsigned short* __restrict__ out,
                                                   int K, int N) {
  __shared__ float lds[64 * 65];
  int z = blockIdx.z;
  in += (size_t)z * K * N;
  out += (size_t)z * K * N;
  int k0 = blockIdx.x * 64, n0 = blockIdx.y * 64;
  int t = threadIdx.x;
#pragma unroll
  for (int j = 0; j < 4; ++j) {
    int idx = j * 256 + t;
    int r = idx >> 4, c = (idx & 15) * 4;
    float4 v = *reinterpret_cast<const float4*>(in + (size_t)(k0 + r) * N + n0 + c);
    lds[r * 65 + c] = v.x;
    lds[r * 65 + c + 1] = v.y;
    lds[r * 65 + c + 2] = v.z;
    lds[r * 65 + c + 3] = v.w;
  }
  __syncthreads();
#pragma unroll
  for (int j = 0; j < 2; ++j) {
    int idx = j * 256 + t;
    int n = idx >> 3, kg = (idx & 7) * 8;
    float a0 = lds[(kg + 0) * 65 + n], a1 = lds[(kg + 1) * 65 + n];
    float a2 = lds[(kg + 2) * 65 + n], a3 = lds[(kg + 3) * 65 + n];
    float a4 = lds[(kg + 4) * 65 + n], a5 = lds[(kg + 5) * 65 + n];
    float a6 = lds[(kg + 6) * 65 + n], a7 = lds[(kg + 7) * 65 + n];
    uint4 o{pk2(a0, a1), pk2(a2, a3), pk2(a4, a5), pk2(a6, a7)};
    *reinterpret_cast<uint4*>(out + (size_t)(n0 + n) * K + k0 + kg) = o;
  }
}

// ---------------- Router ----------------
__global__ __launch_bounds__(256) void router_kernel(const float* __restrict__ x,
                                                     const float* __restrict__ rw,
                                                     int* __restrict__ cnt,
                                                     int* __restrict__ list,
                                                     float* __restrict__ tw) {
  int t = blockIdx.x;
  const float* xr = x + (size_t)t * DD;
  __shared__ float logits[E_N];
  int lane = threadIdx.x & 63, wid = threadIdx.x >> 6;
  for (int ee = 0; ee < 4; ++ee) {
    int e = wid * 4 + ee;
    const float* wr = rw + (size_t)e * DD;
    float p = 0.f;
    for (int d = lane; d < DD; d += 64) p += xr[d] * wr[d];
#pragma unroll
    for (int off = 32; off > 0; off >>= 1) p += __shfl_down(p, off);
    if (lane == 0) logits[e] = p;
  }
  __syncthreads();
  if (threadIdx.x == 0) {
    float mx = -1e30f;
    for (int e = 0; e < E_N; ++e) mx = fmaxf(mx, logits[e]);
    float pe[E_N];
    for (int e = 0; e < E_N; ++e) pe[e] = __expf(logits[e] - mx);
    int idx[TOPK]; float val[TOPK]; float s4 = 0.f;
    unsigned used = 0;
    for (int k = 0; k < TOPK; ++k) {
      int bi = 0; float bv = -1.f;
      for (int e = 0; e < E_N; ++e)
        if (!((used >> e) & 1) && pe[e] > bv) { bv = pe[e]; bi = e; }
      used |= 1u << bi; idx[k] = bi; val[k] = bv; s4 += bv;
    }
    float inv = 1.f / s4;
    for (int k = 0; k < TOPK; ++k) {
      int e2 = idx[k];
      int pos = atomicAdd(&cnt[e2], 1);
      list[e2 * TT + pos] = t * 4 + k;
      tw[t * 4 + k] = val[k] * inv;
    }
  }
}

// ============ 256x256 phase-locked GEMM (m201-style, half-aligned staging) ============
// BM=BN=256, BK=32, 512 threads / 8 waves (2M x 4N); per-wave output 128x64.
// Wave (wm,wn) reads ONLY A-half wm and B-half wn>>1  ->  half-granular staging is safe.
// LDS ring-3 x [A(2 halves 128x32) | B(2 halves)] = 3 x 32KB = 96KB.
// Per tile: 2 phases {reg ds_reads; stage 1 half-pair of tile kt+2; [tile-end vmcnt(4)];
// barrier; setprio+16 MFMA; barrier}. vmcnt counted, never 0 mid-loop.
template <int MODE, int SHIFT>
__device__ __forceinline__ void gemm8(
    const unsigned short* __restrict__ A0, const unsigned short* __restrict__ W0,
    void* __restrict__ O0, const int* lst, const float* __restrict__ tw,
    int M, int Kt, int Nt, int m0, int n0) {
  __shared__ __align__(16) unsigned short lds[3][16384];

  int tid = threadIdx.x, lane = tid & 63, w = tid >> 6;
  int wm = w >> 2, wn = w & 3;

  // staging: thread covers local row tid>>2, chunk-pos tid&3; source chunk swizzled
  int scs = (tid & 3) ^ ((tid >> 3) & 3);
  const unsigned short* pA[2];
  const unsigned short* pB[2];
#pragma unroll
  for (int h = 0; h < 2; ++h) {
    int row = h * 128 + (tid >> 2);
    int ar = min(m0 + row, M - 1);
    int code = lst ? lst[ar] : ar;
    int arow = SHIFT ? (lst ? (code >> 2) : code) : code;
    pA[h] = A0 + (size_t)arow * Kt + scs * 8;
    int br = min(n0 + row, Nt - 1);
    pB[h] = W0 + (size_t)br * Kt + scs * 8;
  }

  auto stage2 = [&](int kt, int h) {
    unsigned short* d = &lds[kt % 3][0];
    GLOAD16(pA[h] + kt * 32, d + h * 4096 + tid * 8);
    GLOAD16(pB[h] + kt * 32, d + 8192 + h * 4096 + tid * 8);
  };

  // fragment offsets (within own half), swizzle matches staging
  int cg = lane >> 4;
  int aoff[2][4], boff[4];
#pragma unroll
  for (int mq = 0; mq < 2; ++mq)
#pragma unroll
    for (int mf = 0; mf < 4; ++mf) {
      int lr = mq * 64 + mf * 16 + (lane & 15);
      aoff[mq][mf] = wm * 4096 + lr * 32 + ((cg ^ ((lr >> 1) & 3)) * 8);
    }
#pragma unroll
  for (int nf = 0; nf < 4; ++nf) {
    int lr = (wn & 1) * 64 + nf * 16 + (lane & 15);
    boff[nf] = 8192 + (wn >> 1) * 4096 + lr * 32 + ((cg ^ ((lr >> 1) & 3)) * 8);
  }

  f32x4 acc[8][4] = {};

  int nk = Kt / 32;
  // prologue: tiles 0,1 fully staged (8 loads); wait tile0's 4, global-validate via barrier
  stage2(0, 0); stage2(0, 1);
  stage2(1, 0); stage2(1, 1);
  VMW(4);
  SBAR();

  for (int kt = 0; kt < nk; ++kt) {
    const unsigned short* L = &lds[kt % 3][0];
    bf16x8 b[4];
#pragma unroll
    for (int nf = 0; nf < 4; ++nf)
      b[nf] = __builtin_bit_cast(bf16x8, *reinterpret_cast<const uint4*>(L + boff[nf]));
#pragma unroll
    for (int ph = 0; ph < 2; ++ph) {
      bf16x8 a[4];
#pragma unroll
      for (int mf = 0; mf < 4; ++mf)
        a[mf] = __builtin_bit_cast(bf16x8, *reinterpret_cast<const uint4*>(L + aoff[ph][mf]));
      if (kt + 2 < nk) stage2(kt + 2, ph);   // half-pair ph of tile kt+2 into buf[(kt+2)%3]
      if (ph == 1) {
        if (kt + 2 < nk) { VMW(4); }         // tile kt+1's 4 stages landed (per-wave)
        else if (kt + 1 < nk) { VMW(0); }    // tail drain
      }
      SBAR();                                 // global validation / phase lockstep
      __builtin_amdgcn_s_setprio(1);
#pragma unroll
      for (int mf = 0; mf < 4; ++mf)
#pragma unroll
        for (int nf = 0; nf < 4; ++nf)
          acc[ph * 4 + mf][nf] = __builtin_amdgcn_mfma_f32_16x16x32_bf16(
              a[mf], b[nf], acc[ph * 4 + mf][nf], 0, 0, 0);
      __builtin_amdgcn_s_setprio(0);
      SBAR();                                 // close phase
    }
  }

  // epilogue (C/D: col=lane&15, row=(lane>>4)*4+q per 16x16 frag)
#pragma unroll
  for (int mq = 0; mq < 2; ++mq)
#pragma unroll
    for (int mf = 0; mf < 4; ++mf)
#pragma unroll
      for (int q = 0; q < 4; ++q) {
        int grow = m0 + wm * 128 + mq * 64 + mf * 16 + (lane >> 4) * 4 + q;
        if (grow < M) {
          int code = lst ? lst[grow] : grow;
          int col = n0 + wn * 64 + (lane & 15);
          if (MODE == 0) {
            unsigned short* Op = (unsigned short*)O0 + (size_t)code * Nt + col;
#pragma unroll
            for (int nf = 0; nf < 4; ++nf)
              if (col + nf * 16 < Nt) Op[nf * 16] = f2bf(acc[mq * 4 + mf][nf][q]);
          } else {
            float scale = tw ? tw[code] : 1.f;
            float* Op = (float*)O0 + (size_t)code * Nt + col;
#pragma unroll
            for (int nf = 0; nf < 4; ++nf)
              if (col + nf * 16 < Nt) Op[nf * 16] = acc[mq * 4 + mf][nf][q] * scale;
          }
        }
      }
}

// ---------------- mega gate+up launch: z=0..15 expert-G, 16 shared-G,
//                  17..32 expert-U, 33 shared-U ----------------
__global__ __launch_bounds__(512, 1) void gu8_kernel(
    const unsigned short* __restrict__ Xb,
    const unsigned short* __restrict__ WgT, const unsigned short* __restrict__ WuT,
    const unsigned short* __restrict__ SgT, const unsigned short* __restrict__ SuT,
    unsigned short* __restrict__ Gx, unsigned short* __restrict__ Ux,
    unsigned short* __restrict__ Gs, unsigned short* __restrict__ Us,
    const int* __restrict__ list, const int* __restrict__ cnt) {
  int bm, bn, z;
  swz_block(bm, bn, z);
  bool up = z >= 17;
  int ze = up ? z - 17 : z;
  const unsigned short* W0;
  unsigned short* O0;
  const int* lst = nullptr;
  int M, Nt;
  if (ze < E_N) {
    M = cnt[ze];
    lst = list + ze * TT;
    Nt = FF;
    W0 = (up ? WuT : WgT) + (size_t)ze * DD * FF;
    O0 = up ? Ux : Gx;
  } else {
    M = TT;
    Nt = FSS;
    W0 = up ? SuT : SgT;
    O0 = up ? Us : Gs;
  }
  int m0 = bm * 256, n0 = bn * 256;
  if (m0 >= M || n0 >= Nt) return;
  gemm8<0, 1>(Xb, W0, O0, lst, nullptr, M, DD, Nt, m0, n0);
}

// ---------------- mega down launch: z=0..15 expert, 16 shared ----------------
__global__ __launch_bounds__(512, 1) void dn8_kernel(
    const unsigned short* __restrict__ Hx, const unsigned short* __restrict__ Hs,
    const unsigned short* __restrict__ WdT, const unsigned short* __restrict__ SdT,
    float* __restrict__ Y, float* __restrict__ Ys,
    const int* __restrict__ list, const int* __restrict__ cnt,
    const float* __restrict__ tw) {
  int bm, bn, z;
  swz_block(bm, bn, z);
  const unsigned short* A0;
  const unsigned short* W0;
  float* O0;
  const int* lst = nullptr;
  const float* sc = nullptr;
  int M, Kt;
  if (z < E_N) {
    M = cnt[z];
    lst = list + z * TT;
    Kt = FF;
    A0 = Hx;
    W0 = WdT + (size_t)z * FF * DD;
    O0 = Y;
    sc = tw;
  } else {
    M = TT;
    Kt = FSS;
    A0 = Hs;
    W0 = SdT;
    O0 = Ys;
  }
  int m0 = bm * 256, n0 = bn * 256;
  if (m0 >= M) return;
  gemm8<1, 0>(A0, W0, O0, lst, sc, M, Kt, DD, m0, n0);
}

// ---------------- h = silu(g) * u, elementwise in-place on u ----------------
__global__ __launch_bounds__(256) void h_kernel(const unsigned short* __restrict__ g,
                                                unsigned short* __restrict__ u) {
  size_t i = ((size_t)blockIdx.x * 256 + threadIdx.x) * 8;
  uint4 gv = *reinterpret_cast<const uint4*>(g + i);
  uint4 uv = *reinterpret_cast<const uint4*>(u + i);
  const unsigned int* gw = reinterpret_cast<const unsigned int*>(&gv);
  const unsigned int* uw = reinterpret_cast<const unsigned int*>(&uv);
  uint4 ov;
  unsigned int* ow = reinterpret_cast<unsigned int*>(&ov);
#pragma unroll
  for (int j = 0; j < 4; ++j) {
    float g0 = bf2f((unsigned short)(gw[j] & 0xffff));
    float g1 = bf2f((unsigned short)(gw[j] >> 16));
    float u0 = bf2f((unsigned short)(uw[j] & 0xffff));
    float u1 = bf2f((unsigned short)(uw[j] >> 16));
    float h0 = (g0 / (1.f + __expf(-g0))) * u0;
    float h1 = (g1 / (1.f + __expf(-g1))) * u1;
    ow[j] = pk2(h0, h1);
  }
  *reinterpret_cast<uint4*>(u + i) = ov;
}

// ---------------- combine ----------------
__global__ __launch_bounds__(256) void combine_kernel(const float* __restrict__ Y,
                                                      const float* __restrict__ Ys,
                                                      float* __restrict__ out) {
  size_t i = ((size_t)blockIdx.x * 256 + threadIdx.x) * 4;
  size_t t = i / DD;
  int d = (int)(i % DD);
  float4 a = *reinterpret_cast<const float4*>(Ys + i);
#pragma unroll
  for (int k = 0; k < 4; ++k) {
    float4 v = *reinterpret_cast<const float4*>(Y + (t * 4 + k) * (size_t)DD + d);
    a.x += v.x; a.y += v.y; a.z += v.z; a.w += v.w;
  }
  *reinterpret_cast<float4*>(out + i) = a;
}

extern "C" void kernel_launch(void* const* d_in, const int* in_sizes, int n_in,
                              void* d_out, int out_size, void* d_ws, size_t ws_size,
                              hipStream_t stream) {
  const float* x  = (const float*)d_in[0];
  const float* rw = (const float*)d_in[1];
  const float* wg = (const float*)d_in[2];
  const float* wu = (const float*)d_in[3];
  const float* wd = (const float*)d_in[4];
  const float* sg = (const float*)d_in[5];
  const float* su = (const float*)d_in[6];
  const float* sd = (const float*)d_in[7];
  float* out = (float*)d_out;

  char* ws = (char*)d_ws;
  size_t off = 0;
  auto alloc = [&](size_t bytes) {
    off = (off + 255) & ~(size_t)255;
    void* p = ws + off;
    off += bytes;
    return p;
  };
  unsigned short* W1 = (unsigned short*)alloc((size_t)E_N * FF * DD * 2);   // 136 MB
  unsigned short* W2 = (unsigned short*)alloc((size_t)E_N * FF * DD * 2);   // 136 MB
  unsigned short* W3 = (unsigned short*)alloc((size_t)FSS * DD * 2);        // 17 MB
  unsigned short* W4 = (unsigned short*)alloc((size_t)FSS * DD * 2);        // 17 MB
  unsigned short* Xb = (unsigned short*)alloc((size_t)TT * DD * 2);
  unsigned short* Gx = (unsigned short*)alloc((size_t)4 * TT * FF * 2);     // raw expert G
  unsigned short* Hx = (unsigned short*)alloc((size_t)4 * TT * FF * 2);     // raw U -> H
  unsigned short* Gs = (unsigned short*)alloc((size_t)TT * FSS * 2);
  unsigned short* Hs = (unsigned short*)alloc((size_t)TT * FSS * 2);
  float* Y  = (float*)alloc((size_t)4 * TT * DD * 4);
  float* Ys = (float*)alloc((size_t)TT * DD * 4);
  float* tw = (float*)alloc((size_t)4 * TT * 4);
  int* cnt  = (int*)alloc(E_N * 4);
  int* list = (int*)alloc((size_t)E_N * TT * 4);
  (void)ws_size; (void)in_sizes; (void)n_in; (void)out_size;

  hipMemsetAsync(cnt, 0, E_N * 4, stream);
  cvt_bf16_kernel<<<TT * DD / 4 / 256, 256, 0, stream>>>(x, Xb);
  router_kernel<<<TT, 256, 0, stream>>>(x, rw, cnt, list, tw);

  // --- gate/up weight transposes: [D][F(S)] -> [F(S)][D] bf16 ---
  tcvt_kernel<<<dim3(DD / 64, FF / 64, E_N), 256, 0, stream>>>(wg, W1, DD, FF);
  tcvt_kernel<<<dim3(DD / 64, FF / 64, E_N), 256, 0, stream>>>(wu, W2, DD, FF);
  tcvt_kernel<<<dim3(DD / 64, FSS / 64, 1), 256, 0, stream>>>(sg, W3, DD, FSS);
  tcvt_kernel<<<dim3(DD / 64, FSS / 64, 1), 256, 0, stream>>>(su, W4, DD, FSS);

  // --- ALL gate+up GEMMs, 256x256 phase-locked (z: 16 eG + 1 sG + 16 eU + 1 sU) ---
  gu8_kernel<<<dim3(TT / 256, FSS / 256, 34), 512, 0, stream>>>(
      Xb, W1, W2, W3, W4, Gx, Hx, Gs, Hs, list, cnt);

  // --- h = silu(g)*u ---
  h_kernel<<<(size_t)4 * TT * FF / 8 / 256, 256, 0, stream>>>(Gx, Hx);
  h_kernel<<<(size_t)TT * FSS / 8 / 256, 256, 0, stream>>>(Gs, Hs);

  // --- down weight transposes (reuse W1/W2) ---
  tcvt_kernel<<<dim3(FF / 64, DD / 64, E_N), 256, 0, stream>>>(wd, W1, FF, DD);
  tcvt_kernel<<<dim3(FSS / 64, DD / 64, 1), 256, 0, stream>>>(sd, W2, FSS, DD);

  // --- both down GEMMs, 256x256 phase-locked (z: 16 expert + 1 shared) ---
  dn8_kernel<<<dim3(TT / 256, DD / 256, 17), 512, 0, stream>>>(
      Hx, Hs, W1, W2, Y, Ys, list, cnt, tw);

  combine_kernel<<<TT * DD / 4 / 256, 256, 0, stream>>>(Y, Ys, out);
}